// Round 7
// baseline (139.962 us; speedup 1.0000x reference)
//
#include <hip/hip_runtime.h>

#define B_ 8
#define A_ 49104
#define C_ 20
#define M_ 32
#define N_ 16
#define AC_ (A_ * C_)     // 982080
#define APB_ 64           // anchors per block
#define NB_ 768           // blocks = ceil(A/64)
#define TPB_ 320          // 5 waves; 64 anchors * 5 float4-chunks = 320 cls tasks

// Workspace: regpart float[B][NB] @0 (24576 B), clspart float[B][NB] @24576,
//            pospart int[B][NB] @49152, ticket counter (unsigned) @73728.
//
// Single fused kernel. Finalization runs in the LAST block (ticket via
// device-scope atomicAdd). The counter is NOT zeroed: the harness poisons ws
// to 0xAA before every launch, so the ticket test is modular —
// (ticket - 0xAAAAAAAA) % NB_ == NB_-1 picks exactly one block for ANY
// starting value (robust even if a rocprof replay skips the re-poison).
//
// R5 lesson (measured): never carry bulk register state across __syncthreads
// (spill -> 12% occupancy); all 16 cls-pass loads are issued inside phase 3
// as one batched vmcnt group (R6, measured good).

__device__ __forceinline__ float cls_term(float e, float p, float alpha) {
    const float pc = fminf(fmaxf(p, 1e-4f), 1.0f - 1e-4f);
    const float ec = fminf(fmaxf(e, 1e-4f), 1.0f - 1e-4f);
    const float bce = -(ec * __logf(pc) + (1.0f - ec) * __logf(1.0f - pc));
    const float df = fabsf(ec - pc);
    return alpha * df * df * bce;
}

__global__ __launch_bounds__(TPB_) void k_main(
        const float* __restrict__ anchors,        // [A,4]
        const float* __restrict__ regress,        // [B,A,4]
        const float* __restrict__ cls,            // [B,A,C]
        const float* __restrict__ ema,            // [B,A,C]
        const float* __restrict__ ema_classes,    // [B,M]
        const float* __restrict__ ema_bboxes,     // [B,M,4]
        const int*   __restrict__ ema_counts,     // [B]
        const float* __restrict__ annotations,    // [B,N,5]
        float* __restrict__ regpart,              // [B,NB]
        float* __restrict__ clspart,              // [B,NB]
        int* __restrict__ pospart,                // [B,NB]
        unsigned* __restrict__ counter,
        float* __restrict__ out)
{
    const int tid = threadIdx.x;
    const int a0 = blockIdx.x * APB_;

    __shared__ float4 sbox[B_][M_];
    __shared__ unsigned char skeep[B_][M_];
    __shared__ float smask[B_][APB_];          // assigned as float mask
    __shared__ float sreg[B_];
    __shared__ int snp[B_];
    __shared__ float pacc[TPB_ / 64][B_];

    // ---- phase 1: stage boxes + keep flags; zero accumulators ----
    if (tid < B_ * M_) {                       // 256 tasks, coalesced
        const int b = tid >> 5, m = tid & 31;
        sbox[b][m] = reinterpret_cast<const float4*>(ema_bboxes)[tid];
        const float clsm = ema_classes[tid];
        bool member = false;
        for (int n = 0; n < N_; ++n)
            member |= (clsm == annotations[b * N_ * 5 + n * 5 + 4]);
        skeep[b][m] = (m < ema_counts[b] && member) ? 1 : 0;
    }
    if (tid < B_) { sreg[tid] = 0.f; snp[tid] = 0; }
    __syncthreads();

    // ---- phase 2: assignment + smooth-L1, all batches ----
    // task = b*64 + al; tasks 64-aligned per wave -> b wave-uniform.
    for (int task = tid; task < B_ * APB_; task += TPB_) {
        const int b = task >> 6, al = task & 63;
        const int a = a0 + al;
        if (a >= A_) continue;
        const float4 anc = reinterpret_cast<const float4*>(anchors)[a];
        const float aw = anc.z - anc.x;
        const float ah = anc.w - anc.y;
        const float area_a = aw * ah;

        float best = -1.0f;
        int barg = 0;
        for (int m = 0; m < M_; ++m) {
            if (!skeep[b][m]) continue;        // wave-uniform
            const float4 bb = sbox[b][m];
            float iw = fminf(anc.z, bb.z) - fmaxf(anc.x, bb.x);
            float ih = fminf(anc.w, bb.w) - fmaxf(anc.y, bb.y);
            iw = fmaxf(iw, 0.f);
            ih = fmaxf(ih, 0.f);
            const float inter = iw * ih;
            const float areab = (bb.z - bb.x) * (bb.w - bb.y);
            const float uni = fmaxf(area_a + areab - inter, 1e-8f);
            const float iou = inter / uni;
            if (iou > best) { best = iou; barg = m; }   // strict >: first-max = jnp.argmax
        }
        const bool has = (best >= 0.0f);       // any kept box -> iou >= 0
        const bool pos = has && (best >= 0.5f);
        smask[b][al] = (has && (best < 0.4f || best >= 0.5f)) ? 1.0f : 0.0f;

        if (pos) {
            const float4 ab = sbox[b][barg];
            float gw = ab.z - ab.x;
            float gh = ab.w - ab.y;
            const float gcx = ab.x + 0.5f * gw;   // center with UNclipped w/h (ref order)
            const float gcy = ab.y + 0.5f * gh;
            gw = fmaxf(gw, 1.0f);
            gh = fmaxf(gh, 1.0f);
            const float acx = anc.x + 0.5f * aw;
            const float acy = anc.y + 0.5f * ah;
            float t[4];
            t[0] = (gcx - acx) / aw / 0.1f;
            t[1] = (gcy - acy) / ah / 0.1f;
            t[2] = __logf(gw / aw) / 0.2f;
            t[3] = __logf(gh / ah) / 0.2f;
            const float4 r = reinterpret_cast<const float4*>(regress)[b * A_ + a];
            const float rr[4] = {r.x, r.y, r.z, r.w};
            float rl = 0.f;
            for (int k = 0; k < 4; ++k) {
                const float d = fabsf(t[k] - rr[k]);
                rl += (d <= (1.0f / 9.0f)) ? 4.5f * d * d : (d - 0.5f / 9.0f);
            }
            atomicAdd(&snp[b], 1);             // LDS atomics, pos anchors are rare
            atomicAdd(&sreg[b], rl);
        }
    }
    __syncthreads();

    // ---- phase 3: classification; all 16 loads in one batched vmcnt group ----
    const int al3 = tid / 5;
    const int ch  = tid % 5;
    const int a3  = a0 + al3;
    float acc[B_];
#pragma unroll
    for (int b = 0; b < B_; ++b) acc[b] = 0.f;

    if (a3 < A_) {
        const size_t cell = (size_t)a3 * C_ + ch * 4;
        float4 e[B_], p[B_];
#pragma unroll
        for (int b = 0; b < B_; ++b) {
            e[b] = *reinterpret_cast<const float4*>(ema + (size_t)b * AC_ + cell);
            p[b] = *reinterpret_cast<const float4*>(cls + (size_t)b * AC_ + cell);
        }
        float sx = 0.f, sy = 0.f, sz = 0.f, sw = 0.f;
#pragma unroll
        for (int b = 0; b < B_; ++b) {
            sx += e[b].x; sy += e[b].y; sz += e[b].z; sw += e[b].w;
        }
        // alpha_sum[a,c] = B*a0 + (a1-a0)*sum_b ema   (bug-faithful batch-sum)
        const float ax = 0.4f + 0.9f * sx;
        const float ay = 0.4f + 0.9f * sy;
        const float az = 0.4f + 0.9f * sz;
        const float aw4 = 0.4f + 0.9f * sw;
#pragma unroll
        for (int b = 0; b < B_; ++b) {
            const float mk = smask[b][al3];    // multiply-mask, no branch
            float s = cls_term(e[b].x, p[b].x, ax);
            s += cls_term(e[b].y, p[b].y, ay);
            s += cls_term(e[b].z, p[b].z, az);
            s += cls_term(e[b].w, p[b].w, aw4);
            acc[b] += mk * s;
        }
    }

    // ---- reduce 5 waves -> LDS -> 8 writers ----
#pragma unroll
    for (int b = 0; b < B_; ++b)
        for (int off = 32; off; off >>= 1)
            acc[b] += __shfl_down(acc[b], off);
    const int wv = tid >> 6;
    if ((tid & 63) == 0) {
#pragma unroll
        for (int b = 0; b < B_; ++b) pacc[wv][b] = acc[b];
    }
    __syncthreads();
    if (tid < B_) {
        float tot = 0.f;
#pragma unroll
        for (int w = 0; w < TPB_ / 64; ++w) tot += pacc[w][tid];
        clspart[tid * NB_ + blockIdx.x] = tot;
        regpart[tid * NB_ + blockIdx.x] = sreg[tid];
        pospart[tid * NB_ + blockIdx.x] = snp[tid];
        __threadfence();                       // release: flush XCD L2 before ticket
    }
    __syncthreads();

    // ---- ticket: exactly one last block proceeds ----
    __shared__ int slast;
    if (tid == 0) {
        const unsigned ticket = atomicAdd(counter, 1u);
        slast = ((ticket - 0xAAAAAAAAu) % (unsigned)NB_) == (unsigned)(NB_ - 1);
    }
    __syncthreads();
    if (!slast) return;
    __threadfence();                           // acquire: see other XCDs' partials

    // ---- finalize (former k_fin), waves 0-3 ----
    __shared__ double scls[B_], sregs[B_];
    __shared__ int snp2[B_];
    if (tid < 256) {
        const int b = tid >> 5;
        const int l = tid & 31;
        double r = 0.0, s = 0.0;
        int p = 0;
#pragma unroll
        for (int k = 0; k < NB_ / 32; ++k) {
            const int i = b * NB_ + l + k * 32;
            r += (double)regpart[i];
            s += (double)clspart[i];
            p += pospart[i];
        }
        for (int off = 16; off; off >>= 1) {
            r += __shfl_down(r, off, 32);
            s += __shfl_down(s, off, 32);
            p += __shfl_down(p, off, 32);
        }
        if (l == 0) { scls[b] = s; sregs[b] = r; snp2[b] = p; }
    }
    __syncthreads();
    if (tid == 0) {
        double c = 0.0, rr = 0.0;
        for (int b2 = 0; b2 < B_; ++b2) {
            const int n = snp2[b2];
            c += scls[b2] / (double)(n > 1 ? n : 1);
            if (n > 0) rr += sregs[b2] / (4.0 * (double)n);
        }
        out[0] = (float)(c / (double)B_);
        out[1] = (float)(rr / (double)B_);
    }
}

extern "C" void kernel_launch(void* const* d_in, const int* in_sizes, int n_in,
                              void* d_out, int out_size, void* d_ws, size_t ws_size,
                              hipStream_t stream) {
    const float* classifications     = (const float*)d_in[0];
    const float* regressions         = (const float*)d_in[1];
    const float* anchors             = (const float*)d_in[2];
    const float* ema_classifications = (const float*)d_in[3];
    const float* ema_classes         = (const float*)d_in[4];
    const float* ema_bboxes          = (const float*)d_in[5];
    const int*   ema_counts          = (const int*)d_in[6];
    const float* annotations         = (const float*)d_in[7];
    float* out = (float*)d_out;

    char* ws = (char*)d_ws;
    float*    regpart = (float*)ws;                  // [B_*NB_]
    float*    clspart = (float*)(ws + 24576);        // [B_*NB_]
    int*      pospart = (int*)(ws + 49152);          // [B_*NB_]
    unsigned* counter = (unsigned*)(ws + 73728);

    k_main<<<NB_, TPB_, 0, stream>>>(anchors, regressions, classifications,
                                     ema_classifications, ema_classes, ema_bboxes,
                                     ema_counts, annotations,
                                     regpart, clspart, pospart, counter, out);
}

// Round 8
// 117.502 us; speedup vs baseline: 1.1912x; 1.1912x over previous
//
#include <hip/hip_runtime.h>

#define B_ 8
#define A_ 49104
#define C_ 20
#define M_ 32
#define N_ 16
#define AC_ (A_ * C_)     // 982080
#define APB_ 64           // anchors per block (fused kernel)
#define NB_ 768           // blocks = ceil(A/64)
#define TPB_ 320          // 5 waves; 64 anchors * 5 float4-chunks = 320 cls tasks

// Workspace: regpart float[B][NB] @0 (24576 B), clspart float[B][NB] @24576,
//            pospart int[B][NB] @49152.
//
// Measured session lessons baked into this structure:
//  * R1: one contended f64 atomic per block serializes ~32ns each -> per-block
//    private partial slots + separate reduce kernel.
//  * R5: never carry bulk register state across __syncthreads (spill ->
//    occupancy 12%); compiler drains vmcnt(0) at barriers anyway.
//  * R6: issue all 16 cls-pass float4 loads as ONE batched vmcnt group inside
//    phase 3 (not 8 divergent load-use chains).
//  * R7: single-kernel last-block finalize needs device-scope __threadfence,
//    which on gfx950 (non-coherent per-XCD L2) costs ~37us across 768 blocks.
//    Two kernels + implicit inter-launch sync is strictly cheaper.

__device__ __forceinline__ float cls_term(float e, float p, float alpha) {
    const float pc = fminf(fmaxf(p, 1e-4f), 1.0f - 1e-4f);
    const float ec = fminf(fmaxf(e, 1e-4f), 1.0f - 1e-4f);
    const float bce = -(ec * __logf(pc) + (1.0f - ec) * __logf(1.0f - pc));
    const float df = fabsf(ec - pc);
    return alpha * df * df * bce;
}

__global__ __launch_bounds__(TPB_) void k_main(
        const float* __restrict__ anchors,        // [A,4]
        const float* __restrict__ regress,        // [B,A,4]
        const float* __restrict__ cls,            // [B,A,C]
        const float* __restrict__ ema,            // [B,A,C]
        const float* __restrict__ ema_classes,    // [B,M]
        const float* __restrict__ ema_bboxes,     // [B,M,4]
        const int*   __restrict__ ema_counts,     // [B]
        const float* __restrict__ annotations,    // [B,N,5]
        float* __restrict__ regpart,              // [B,NB]
        float* __restrict__ clspart,              // [B,NB]
        int* __restrict__ pospart)                // [B,NB]
{
    const int tid = threadIdx.x;
    const int a0 = blockIdx.x * APB_;

    __shared__ float4 sbox[B_][M_];
    __shared__ unsigned char skeep[B_][M_];
    __shared__ float smask[B_][APB_];          // assigned as float mask
    __shared__ float sreg[B_];
    __shared__ int snp[B_];
    __shared__ float pacc[TPB_ / 64][B_];

    // ---- phase 1: stage boxes + keep flags; zero accumulators ----
    if (tid < B_ * M_) {                       // 256 tasks, coalesced
        const int b = tid >> 5, m = tid & 31;
        sbox[b][m] = reinterpret_cast<const float4*>(ema_bboxes)[tid];
        const float clsm = ema_classes[tid];
        bool member = false;
        for (int n = 0; n < N_; ++n)
            member |= (clsm == annotations[b * N_ * 5 + n * 5 + 4]);
        skeep[b][m] = (m < ema_counts[b] && member) ? 1 : 0;
    }
    if (tid < B_) { sreg[tid] = 0.f; snp[tid] = 0; }
    __syncthreads();

    // ---- phase 2: assignment + smooth-L1 for owned anchors, all batches ----
    // task = b*64 + al; tasks are 64-aligned per wave -> b wave-uniform.
    for (int task = tid; task < B_ * APB_; task += TPB_) {
        const int b = task >> 6, al = task & 63;
        const int a = a0 + al;
        if (a >= A_) continue;
        const float4 anc = reinterpret_cast<const float4*>(anchors)[a];
        const float aw = anc.z - anc.x;
        const float ah = anc.w - anc.y;
        const float area_a = aw * ah;

        float best = -1.0f;
        int barg = 0;
        for (int m = 0; m < M_; ++m) {
            if (!skeep[b][m]) continue;        // wave-uniform
            const float4 bb = sbox[b][m];
            float iw = fminf(anc.z, bb.z) - fmaxf(anc.x, bb.x);
            float ih = fminf(anc.w, bb.w) - fmaxf(anc.y, bb.y);
            iw = fmaxf(iw, 0.f);
            ih = fmaxf(ih, 0.f);
            const float inter = iw * ih;
            const float areab = (bb.z - bb.x) * (bb.w - bb.y);
            const float uni = fmaxf(area_a + areab - inter, 1e-8f);
            const float iou = inter / uni;
            if (iou > best) { best = iou; barg = m; }   // strict >: first-max = jnp.argmax
        }
        const bool has = (best >= 0.0f);       // any kept box -> iou >= 0
        const bool pos = has && (best >= 0.5f);
        smask[b][al] = (has && (best < 0.4f || best >= 0.5f)) ? 1.0f : 0.0f;

        if (pos) {
            const float4 ab = sbox[b][barg];
            float gw = ab.z - ab.x;
            float gh = ab.w - ab.y;
            const float gcx = ab.x + 0.5f * gw;   // center with UNclipped w/h (ref order)
            const float gcy = ab.y + 0.5f * gh;
            gw = fmaxf(gw, 1.0f);
            gh = fmaxf(gh, 1.0f);
            const float acx = anc.x + 0.5f * aw;
            const float acy = anc.y + 0.5f * ah;
            float t[4];
            t[0] = (gcx - acx) / aw / 0.1f;
            t[1] = (gcy - acy) / ah / 0.1f;
            t[2] = __logf(gw / aw) / 0.2f;
            t[3] = __logf(gh / ah) / 0.2f;
            const float4 r = reinterpret_cast<const float4*>(regress)[b * A_ + a];
            const float rr[4] = {r.x, r.y, r.z, r.w};
            float rl = 0.f;
            for (int k = 0; k < 4; ++k) {
                const float d = fabsf(t[k] - rr[k]);
                rl += (d <= (1.0f / 9.0f)) ? 4.5f * d * d : (d - 0.5f / 9.0f);
            }
            atomicAdd(&snp[b], 1);             // LDS atomics, pos anchors are rare
            atomicAdd(&sreg[b], rl);
        }
    }
    __syncthreads();

    // ---- phase 3: classification; all 16 loads issued unconditionally ----
    // thread t -> anchor a0 + t/5, float4 chunk t%5: contiguous 16B/lane.
    const int al3 = tid / 5;
    const int ch  = tid % 5;
    const int a3  = a0 + al3;
    float acc[B_];
#pragma unroll
    for (int b = 0; b < B_; ++b) acc[b] = 0.f;

    if (a3 < A_) {
        const size_t cell = (size_t)a3 * C_ + ch * 4;
        float4 e[B_], p[B_];
#pragma unroll
        for (int b = 0; b < B_; ++b) {
            e[b] = *reinterpret_cast<const float4*>(ema + (size_t)b * AC_ + cell);
            p[b] = *reinterpret_cast<const float4*>(cls + (size_t)b * AC_ + cell);
        }
        float sx = 0.f, sy = 0.f, sz = 0.f, sw = 0.f;
#pragma unroll
        for (int b = 0; b < B_; ++b) {
            sx += e[b].x; sy += e[b].y; sz += e[b].z; sw += e[b].w;
        }
        // alpha_sum[a,c] = B*a0 + (a1-a0)*sum_b ema   (bug-faithful batch-sum)
        const float ax = 0.4f + 0.9f * sx;
        const float ay = 0.4f + 0.9f * sy;
        const float az = 0.4f + 0.9f * sz;
        const float aw4 = 0.4f + 0.9f * sw;
#pragma unroll
        for (int b = 0; b < B_; ++b) {
            const float mk = smask[b][al3];    // multiply-mask, no branch
            float s = cls_term(e[b].x, p[b].x, ax);
            s += cls_term(e[b].y, p[b].y, ay);
            s += cls_term(e[b].z, p[b].z, az);
            s += cls_term(e[b].w, p[b].w, aw4);
            acc[b] += mk * s;
        }
    }

    // ---- reduce: 5 waves -> LDS -> 8 writers ----
#pragma unroll
    for (int b = 0; b < B_; ++b)
        for (int off = 32; off; off >>= 1)
            acc[b] += __shfl_down(acc[b], off);
    const int wv = tid >> 6;
    if ((tid & 63) == 0) {
#pragma unroll
        for (int b = 0; b < B_; ++b) pacc[wv][b] = acc[b];
    }
    __syncthreads();
    if (tid < B_) {
        float tot = 0.f;
#pragma unroll
        for (int w = 0; w < TPB_ / 64; ++w) tot += pacc[w][tid];
        clspart[tid * NB_ + blockIdx.x] = tot;
        regpart[tid * NB_ + blockIdx.x] = sreg[tid];
        pospart[tid * NB_ + blockIdx.x] = snp[tid];
    }
}

// Single block, one flat phase: b = tid/32, 32 lanes stride the batch's
// partials (72 independent loads/thread, latency hidden), width-32 shuffle
// reduce, double accumulation for the final weighted sums.
__global__ __launch_bounds__(256) void k_fin(
        const float* __restrict__ regpart,    // [B,NB]
        const float* __restrict__ clspart,    // [B,NB]
        const int* __restrict__ pospart,      // [B,NB]
        float* __restrict__ out)
{
    const int tid = threadIdx.x;
    const int b = tid >> 5;
    const int l = tid & 31;

    double r = 0.0, s = 0.0;
    int p = 0;
#pragma unroll
    for (int k = 0; k < NB_ / 32; ++k) {
        const int i = b * NB_ + l + k * 32;
        r += (double)regpart[i];
        s += (double)clspart[i];
        p += pospart[i];
    }
    for (int off = 16; off; off >>= 1) {
        r += __shfl_down(r, off, 32);
        s += __shfl_down(s, off, 32);
        p += __shfl_down(p, off, 32);
    }

    __shared__ double scls[B_], sregs[B_];
    __shared__ int snp[B_];
    if (l == 0) { scls[b] = s; sregs[b] = r; snp[b] = p; }
    __syncthreads();

    if (tid == 0) {
        double c = 0.0, rr = 0.0;
        for (int b2 = 0; b2 < B_; ++b2) {
            const int n = snp[b2];
            c += scls[b2] / (double)(n > 1 ? n : 1);
            if (n > 0) rr += sregs[b2] / (4.0 * (double)n);
        }
        out[0] = (float)(c / (double)B_);
        out[1] = (float)(rr / (double)B_);
    }
}

extern "C" void kernel_launch(void* const* d_in, const int* in_sizes, int n_in,
                              void* d_out, int out_size, void* d_ws, size_t ws_size,
                              hipStream_t stream) {
    const float* classifications     = (const float*)d_in[0];
    const float* regressions         = (const float*)d_in[1];
    const float* anchors             = (const float*)d_in[2];
    const float* ema_classifications = (const float*)d_in[3];
    const float* ema_classes         = (const float*)d_in[4];
    const float* ema_bboxes          = (const float*)d_in[5];
    const int*   ema_counts          = (const int*)d_in[6];
    const float* annotations         = (const float*)d_in[7];
    float* out = (float*)d_out;

    char* ws = (char*)d_ws;
    float* regpart = (float*)ws;                  // [B_*NB_]
    float* clspart = (float*)(ws + 24576);        // [B_*NB_]
    int*   pospart = (int*)(ws + 49152);          // [B_*NB_]

    k_main<<<NB_, TPB_, 0, stream>>>(anchors, regressions, classifications,
                                     ema_classifications, ema_classes, ema_bboxes,
                                     ema_counts, annotations,
                                     regpart, clspart, pospart);

    k_fin<<<1, 256, 0, stream>>>(regpart, clspart, pospart, out);
}